// Round 1
// baseline (176.573 us; speedup 1.0000x reference)
//
#include <hip/hip_runtime.h>

// Problem constants from the reference: x (8,320,320) f32, u (8,12,320,320,2) f32.
// out (8,12,320,320) f32.
#define PP 8
#define FF 12
#define MM 320
#define NN 320

__global__ __launch_bounds__(256) void warp_fwd_kernel(
    const float* __restrict__ x,
    const float2* __restrict__ u,
    float* __restrict__ out,
    int total)
{
    int idx = blockIdx.x * blockDim.x + threadIdx.x;
    if (idx >= total) return;

    // idx -> (p, f, i, j); out is (P,F,M,N) row-major flat.
    int ij = idx % (MM * NN);
    int pf = idx / (MM * NN);
    int p  = pf / FF;
    int i  = ij / NN;
    int j  = ij - i * NN;

    float2 uv = u[idx];                 // uv.x = dx (cols), uv.y = dy (rows)
    float sx = (float)j + uv.x;
    float sy = (float)i + uv.y;
    float x0 = floorf(sx);
    float y0 = floorf(sy);
    float wx = sx - x0;
    float wy = sy - y0;
    int x0i = (int)x0;
    int y0i = (int)y0;

    const float* __restrict__ img = x + p * (MM * NN);

    // Branchless predicated gather with clamped (always in-bounds) addresses.
    int xc0 = min(max(x0i,     0), NN - 1);
    int xc1 = min(max(x0i + 1, 0), NN - 1);
    int yc0 = min(max(y0i,     0), MM - 1);
    int yc1 = min(max(y0i + 1, 0), MM - 1);
    bool vx0 = (x0i >= 0)     & (x0i < NN);
    bool vx1 = (x0i + 1 >= 0) & (x0i + 1 < NN);
    bool vy0 = (y0i >= 0)     & (y0i < MM);
    bool vy1 = (y0i + 1 >= 0) & (y0i + 1 < MM);

    int r0 = yc0 * NN;
    int r1 = yc1 * NN;
    float v00 = (vy0 & vx0) ? img[r0 + xc0] : 0.0f;
    float v01 = (vy0 & vx1) ? img[r0 + xc1] : 0.0f;
    float v10 = (vy1 & vx0) ? img[r1 + xc0] : 0.0f;
    float v11 = (vy1 & vx1) ? img[r1 + xc1] : 0.0f;

    float omwx = 1.0f - wx;
    float omwy = 1.0f - wy;
    out[idx] = (v00 * omwx + v01 * wx) * omwy
             + (v10 * omwx + v11 * wx) * wy;
}

extern "C" void kernel_launch(void* const* d_in, const int* in_sizes, int n_in,
                              void* d_out, int out_size, void* d_ws, size_t ws_size,
                              hipStream_t stream) {
    const float*  x = (const float*)d_in[0];
    const float2* u = (const float2*)d_in[1];
    float* out = (float*)d_out;

    int total = out_size;  // 8*12*320*320 = 9,830,400
    int block = 256;
    int grid = (total + block - 1) / block;
    warp_fwd_kernel<<<grid, block, 0, stream>>>(x, u, out, total);
}